// Round 1
// baseline (2254.552 us; speedup 1.0000x reference)
//
#include <hip/hip_runtime.h>
#include <math.h>

// Problem constants (NSMCell): N=50000, E=800000, H=128, P=8, B=512
#define H_DIM 128
#define NPROP 8
#define NGRAPHS 512
#define HCHUNK 8  // h-chunk per node-kernel block.y

// ---------------------------------------------------------------------------
// Kernel 1: prop_sim = softmax(prop_embeds @ instruction)   [8]
// 1 block, 512 threads = 8 waves, wave p handles property p.
__global__ void prep_prop_sim(const float* __restrict__ prop_embeds,
                              const float* __restrict__ instruction,
                              float* __restrict__ prop_sim) {
  __shared__ float dots[NPROP];
  int wave = threadIdx.x >> 6;
  int lane = threadIdx.x & 63;
  float v = prop_embeds[wave * H_DIM + lane] * instruction[lane] +
            prop_embeds[wave * H_DIM + 64 + lane] * instruction[64 + lane];
#pragma unroll
  for (int off = 32; off > 0; off >>= 1) v += __shfl_down(v, off);
  if (lane == 0) dots[wave] = v;
  __syncthreads();
  if (threadIdx.x == 0) {
    float m = dots[0];
    for (int p = 1; p < NPROP; ++p) m = fmaxf(m, dots[p]);
    float e[NPROP], s = 0.f;
    for (int p = 0; p < NPROP; ++p) { e[p] = expf(dots[p] - m); s += e[p]; }
    for (int p = 0; p < NPROP; ++p) prop_sim[p] = e[p] / s;
  }
}

// ---------------------------------------------------------------------------
// Kernel 2: fold prop_sim[p] (p<7) and instruction[h] into the weights.
// Wout[p][h][k] = (p<7 ? prop_sim[p] : 1) * instruction[h] * Ws[p][h][k]
// 8*128*128 = 131072 elements; grid 512 x 256.
__global__ void prep_scale_weights(const float* __restrict__ Ws,
                                   const float* __restrict__ instruction,
                                   const float* __restrict__ prop_sim,
                                   float* __restrict__ Wout) {
  int idx = blockIdx.x * 256 + threadIdx.x;  // < 131072
  int p = idx >> 14;
  int h = (idx >> 7) & 127;
  float s = (p < 7) ? prop_sim[p] : 1.0f;
  Wout[idx] = s * instruction[h] * Ws[idx];
}

// ---------------------------------------------------------------------------
// Kernel 3: node pass -> state_logits[n] += sum_{h in chunk} W_state[h]*elu(y[h])
// y[h] = sum_p sum_k Aw[p][h][k] * attrs[n][p][k]     (Aw already scaled)
// Thread-per-node; x row (128 fp32) in VGPRs; weight rows are wave-uniform.
__global__ void __launch_bounds__(256) node_kernel(
    const float* __restrict__ node_attrs,  // [N][7][128]
    const float* __restrict__ Aw,          // [7][128][128] scaled
    const float* __restrict__ W_state,     // [128]
    float* __restrict__ state_logits,      // [N] (zero-initialized)
    int N) {
  int n = blockIdx.x * blockDim.x + threadIdx.x;
  if (n >= N) return;
  int hc = blockIdx.y;  // 0..15, handles h in [hc*8, hc*8+8)

  float acc[HCHUNK];
#pragma unroll
  for (int i = 0; i < HCHUNK; ++i) acc[i] = 0.f;

#pragma unroll 1
  for (int p = 0; p < 7; ++p) {
    float x[H_DIM];
    const float4* xr =
        reinterpret_cast<const float4*>(node_attrs + ((size_t)n * 7 + p) * H_DIM);
#pragma unroll
    for (int j = 0; j < H_DIM / 4; ++j) {
      float4 v = xr[j];
      x[4 * j + 0] = v.x; x[4 * j + 1] = v.y;
      x[4 * j + 2] = v.z; x[4 * j + 3] = v.w;
    }
    const float* Ap = Aw + p * (H_DIM * H_DIM) + hc * HCHUNK * H_DIM;
#pragma unroll
    for (int hh = 0; hh < HCHUNK; ++hh) {
      const float* row = Ap + hh * H_DIM;
      float a0 = 0.f, a1 = 0.f, a2 = 0.f, a3 = 0.f;
#pragma unroll
      for (int k = 0; k < H_DIM; k += 4) {
        a0 += row[k + 0] * x[k + 0];
        a1 += row[k + 1] * x[k + 1];
        a2 += row[k + 2] * x[k + 2];
        a3 += row[k + 3] * x[k + 3];
      }
      acc[hh] += (a0 + a1) + (a2 + a3);
    }
  }
  float partial = 0.f;
#pragma unroll
  for (int hh = 0; hh < HCHUNK; ++hh) {
    int h = hc * HCHUNK + hh;
    float y = acc[hh];
    float sc = (y > 0.f) ? y : (expf(y) - 1.f);  // elu
    partial += W_state[h] * sc;
  }
  atomicAdd(state_logits + n, partial);
}

// ---------------------------------------------------------------------------
// Kernel 4: edge pass -> rel_logits[dst] += dist[src] * (W_rel . elu(Bw @ x_e))
// Thread-per-edge; x row (128 fp32) in VGPRs; Bw rows wave-uniform.
__global__ void __launch_bounds__(256) edge_kernel(
    const float* __restrict__ edge_attrs,  // [E][128]
    const float* __restrict__ Bw,          // [128][128] = instr[h]*Ws[7][h][k]
    const float* __restrict__ W_relation,  // [128]
    const float* __restrict__ distribution,// [N]
    const int* __restrict__ src_idx,       // [E]
    const int* __restrict__ dst_idx,       // [E]
    float* __restrict__ rel_logits,        // [N] (zero-initialized)
    int E) {
  int e = blockIdx.x * blockDim.x + threadIdx.x;
  if (e >= E) return;

  float x[H_DIM];
  const float4* xr = reinterpret_cast<const float4*>(edge_attrs + (size_t)e * H_DIM);
#pragma unroll
  for (int j = 0; j < H_DIM / 4; ++j) {
    float4 v = xr[j];
    x[4 * j + 0] = v.x; x[4 * j + 1] = v.y;
    x[4 * j + 2] = v.z; x[4 * j + 3] = v.w;
  }

  float s_e = 0.f;
#pragma unroll 1
  for (int h = 0; h < H_DIM; ++h) {
    const float* row = Bw + h * H_DIM;
    float a0 = 0.f, a1 = 0.f, a2 = 0.f, a3 = 0.f;
#pragma unroll
    for (int k = 0; k < H_DIM; k += 4) {
      a0 += row[k + 0] * x[k + 0];
      a1 += row[k + 1] * x[k + 1];
      a2 += row[k + 2] * x[k + 2];
      a3 += row[k + 3] * x[k + 3];
    }
    float y = (a0 + a1) + (a2 + a3);
    float sc = (y > 0.f) ? y : (expf(y) - 1.f);  // elu
    s_e += W_relation[h] * sc;
  }
  float v = distribution[src_idx[e]] * s_e;
  atomicAdd(rel_logits + dst_idx[e], v);
}

// ---------------------------------------------------------------------------
// Kernel 5: per-graph softmaxes + combine.
// One block per graph; node_graph is sorted so binary-search the range.
__device__ __forceinline__ float wave_red_max(float v) {
#pragma unroll
  for (int off = 32; off > 0; off >>= 1) v = fmaxf(v, __shfl_down(v, off));
  return v;
}
__device__ __forceinline__ float wave_red_sum(float v) {
#pragma unroll
  for (int off = 32; off > 0; off >>= 1) v += __shfl_down(v, off);
  return v;
}

__global__ void finalize_kernel(const float* __restrict__ state_logits,
                                const float* __restrict__ rel_logits,
                                const int* __restrict__ node_graph,
                                const float* __restrict__ prop_sim,
                                float* __restrict__ out, int N) {
  int g = blockIdx.x;
  __shared__ int bounds[2];
  if (threadIdx.x == 0) {
    int a = 0, b = N;
    while (a < b) { int m = (a + b) >> 1; if (node_graph[m] < g) a = m + 1; else b = m; }
    bounds[0] = a;
    b = N;
    while (a < b) { int m = (a + b) >> 1; if (node_graph[m] < g + 1) a = m + 1; else b = m; }
    bounds[1] = a;
  }
  __syncthreads();
  int lo = bounds[0], hi = bounds[1];
  if (lo >= hi) return;

  int lane = threadIdx.x & 63, w = threadIdx.x >> 6;
  __shared__ float redS[4], redR[4];

  // pass 1: maxes
  float mS = -3.0e38f, mR = -3.0e38f;
  for (int i = lo + threadIdx.x; i < hi; i += blockDim.x) {
    mS = fmaxf(mS, state_logits[i]);
    mR = fmaxf(mR, rel_logits[i]);
  }
  mS = wave_red_max(mS); mR = wave_red_max(mR);
  if (lane == 0) { redS[w] = mS; redR[w] = mR; }
  __syncthreads();
  mS = fmaxf(fmaxf(redS[0], redS[1]), fmaxf(redS[2], redS[3]));
  mR = fmaxf(fmaxf(redR[0], redR[1]), fmaxf(redR[2], redR[3]));
  __syncthreads();

  // pass 2: sums of exp
  float sS = 0.f, sR = 0.f;
  for (int i = lo + threadIdx.x; i < hi; i += blockDim.x) {
    sS += expf(state_logits[i] - mS);
    sR += expf(rel_logits[i] - mR);
  }
  sS = wave_red_sum(sS); sR = wave_red_sum(sR);
  if (lane == 0) { redS[w] = sS; redR[w] = sR; }
  __syncthreads();
  sS = redS[0] + redS[1] + redS[2] + redS[3];
  sR = redR[0] + redR[1] + redR[2] + redR[3];

  float p_rel = prop_sim[NPROP - 1];
  float invS = 1.0f / sS, invR = 1.0f / sR;
  for (int i = lo + threadIdx.x; i < hi; i += blockDim.x) {
    float ps = expf(state_logits[i] - mS) * invS;
    float pr = expf(rel_logits[i] - mR) * invR;
    out[i] = p_rel * pr + (1.0f - p_rel) * ps;
  }
}

// ---------------------------------------------------------------------------
extern "C" void kernel_launch(void* const* d_in, const int* in_sizes, int n_in,
                              void* d_out, int out_size, void* d_ws, size_t ws_size,
                              hipStream_t stream) {
  const float* node_attrs   = (const float*)d_in[0];  // [N][7][128]
  const float* edge_attrs   = (const float*)d_in[1];  // [E][128]
  const float* instruction  = (const float*)d_in[2];  // [128]
  const float* prop_embeds  = (const float*)d_in[3];  // [8][128]
  const float* distribution = (const float*)d_in[4];  // [N]
  const float* Ws_property  = (const float*)d_in[5];  // [8][128][128]
  const float* W_state      = (const float*)d_in[6];  // [128]
  const float* W_relation   = (const float*)d_in[7];  // [128]
  const int*   edge_indices = (const int*)d_in[8];    // [2][E]
  const int*   node_graph   = (const int*)d_in[9];    // [N] sorted

  int N = in_sizes[4];
  int E = in_sizes[1] / H_DIM;
  float* out = (float*)d_out;

  // workspace layout (floats)
  float* ws = (float*)d_ws;
  float* prop_sim     = ws;                      // 8 (pad to 64)
  float* Wsc          = ws + 64;                 // 8*128*128 = 131072
  float* state_logits = Wsc + NPROP * H_DIM * H_DIM;  // N
  float* rel_logits   = state_logits + N;        // N

  // zero the two logit accumulators (ws is poisoned 0xAA before every launch)
  hipMemsetAsync(state_logits, 0, sizeof(float) * 2 * (size_t)N, stream);

  prep_prop_sim<<<1, 512, 0, stream>>>(prop_embeds, instruction, prop_sim);
  prep_scale_weights<<<NPROP * H_DIM * H_DIM / 256, 256, 0, stream>>>(
      Ws_property, instruction, prop_sim, Wsc);

  dim3 ngrid((N + 255) / 256, H_DIM / HCHUNK);  // 196 x 16
  node_kernel<<<ngrid, 256, 0, stream>>>(node_attrs, Wsc, W_state, state_logits, N);

  edge_kernel<<<(E + 255) / 256, 256, 0, stream>>>(
      edge_attrs, Wsc + 7 * H_DIM * H_DIM, W_relation, distribution,
      edge_indices, edge_indices + E, rel_logits, E);

  finalize_kernel<<<NGRAPHS, 256, 0, stream>>>(state_logits, rel_logits,
                                               node_graph, prop_sim, out, N);
}

// Round 2
// 976.225 us; speedup vs baseline: 2.3095x; 2.3095x over previous
//
#include <hip/hip_runtime.h>
#include <math.h>

// NSMCell: N=50000, E=800000, H=128, P=8, B=512
#define H_DIM 128
#define NPROP 8
#define NGRAPHS 512
#define LDS_STRIDE 136  // 128 ushorts + 8 pad -> 272B rows, keeps b128 ops at bank floor

typedef short short8 __attribute__((ext_vector_type(8)));
typedef float f32x4 __attribute__((ext_vector_type(4)));
typedef unsigned short ushort_t;

// split fp32 -> bf16 hi + bf16 lo (hi truncated, lo rounded): ~17-bit effective mantissa
__device__ __forceinline__ void split_bf16(float x, ushort_t& hb, ushort_t& lb) {
  unsigned u = __float_as_uint(x);
  hb = (ushort_t)(u >> 16);
  float hf = __uint_as_float(u & 0xFFFF0000u);
  float lf = x - hf;
  unsigned ul = __float_as_uint(lf);
  lb = (ushort_t)((ul + 0x8000u) >> 16);
}

__device__ __forceinline__ float elu_f(float y) {
  return y > 0.f ? y : (__expf(y) - 1.f);
}

// ---------------------------------------------------------------------------
// prop_sim = softmax(prop_embeds @ instruction)
__global__ void prep_prop_sim(const float* __restrict__ prop_embeds,
                              const float* __restrict__ instruction,
                              float* __restrict__ prop_sim) {
  __shared__ float dots[NPROP];
  int wave = threadIdx.x >> 6;
  int lane = threadIdx.x & 63;
  float v = prop_embeds[wave * H_DIM + lane] * instruction[lane] +
            prop_embeds[wave * H_DIM + 64 + lane] * instruction[64 + lane];
#pragma unroll
  for (int off = 32; off > 0; off >>= 1) v += __shfl_down(v, off);
  if (lane == 0) dots[wave] = v;
  __syncthreads();
  if (threadIdx.x == 0) {
    float m = dots[0];
    for (int p = 1; p < NPROP; ++p) m = fmaxf(m, dots[p]);
    float e[NPROP], s = 0.f;
    for (int p = 0; p < NPROP; ++p) { e[p] = expf(dots[p] - m); s += e[p]; }
    for (int p = 0; p < NPROP; ++p) prop_sim[p] = e[p] / s;
  }
}

// ---------------------------------------------------------------------------
// Fold prop_sim[p]*instruction[h] into weights; emit bf16 hi/lo split.
__global__ void prep_weights(const float* __restrict__ Ws,
                             const float* __restrict__ instruction,
                             const float* __restrict__ prop_sim,
                             ushort_t* __restrict__ Wh,
                             ushort_t* __restrict__ Wl) {
  int idx = blockIdx.x * 256 + threadIdx.x;  // < 131072
  int p = idx >> 14;
  int h = (idx >> 7) & 127;
  float s = (p < 7) ? prop_sim[p] : 1.0f;
  float w = s * instruction[h] * Ws[idx];
  ushort_t hb, lb;
  split_bf16(w, hb, lb);
  Wh[idx] = hb;
  Wl[idx] = lb;
}

// ---------------------------------------------------------------------------
// Edge pass (MFMA): C[h,edge] = Wsc[7] @ X^T for a 128-edge tile, then
// s_e = sum_h W_rel[h]*elu(C), scatter dist[src]*s_e to rel_logits[dst].
// A = weights (M=h), B = edge rows (N=edge); both operands are contiguous
// 8x-k slices -> ds_read_b128 / 16B global loads. 3-product bf16 split.
__global__ void __launch_bounds__(256) edge_mfma_kernel(
    const float* __restrict__ edge_attrs,   // [E][128]
    const ushort_t* __restrict__ Wh,        // [128][128] (p=7 slab, scaled)
    const ushort_t* __restrict__ Wl,
    const float* __restrict__ W_relation,   // [128]
    const float* __restrict__ distribution, // [N]
    const int* __restrict__ src_idx,        // [E]
    const int* __restrict__ dst_idx,        // [E]
    float* __restrict__ rel_logits) {       // [N] zero-init
  __shared__ __align__(16) ushort_t Xh[128 * LDS_STRIDE];
  __shared__ __align__(16) ushort_t Xl[128 * LDS_STRIDE];
  const int t = threadIdx.x;
  const long tile_base = (long)blockIdx.x * 128;

  // stage 128x128 fp32 -> bf16 hi/lo LDS (coalesced 16B/lane)
  const float4* gx = (const float4*)(edge_attrs + tile_base * H_DIM);
#pragma unroll
  for (int i = 0; i < 16; ++i) {
    int f = i * 256 + t;
    float4 v = gx[f];
    int row = f >> 5;
    int k4 = (f & 31) * 4;
    ushort4 h4, l4;
    split_bf16(v.x, h4.x, l4.x);
    split_bf16(v.y, h4.y, l4.y);
    split_bf16(v.z, h4.z, l4.z);
    split_bf16(v.w, h4.w, l4.w);
    int idx = row * LDS_STRIDE + k4;
    *(ushort4*)&Xh[idx] = h4;
    *(ushort4*)&Xl[idx] = l4;
  }
  __syncthreads();

  const int lane = t & 63;
  const int wave = t >> 6;
  const int col = lane & 15;
  const int quad = lane >> 4;

  f32x4 acc[8][2];
#pragma unroll
  for (int m = 0; m < 8; ++m) {
    acc[m][0] = (f32x4){0.f, 0.f, 0.f, 0.f};
    acc[m][1] = (f32x4){0.f, 0.f, 0.f, 0.f};
  }

  const int r0 = wave * 32 + col;
#pragma unroll
  for (int ks = 0; ks < 4; ++ks) {
    const int kk = ks * 32 + quad * 8;
    short8 b0h = *(const short8*)&Xh[r0 * LDS_STRIDE + kk];
    short8 b0l = *(const short8*)&Xl[r0 * LDS_STRIDE + kk];
    short8 b1h = *(const short8*)&Xh[(r0 + 16) * LDS_STRIDE + kk];
    short8 b1l = *(const short8*)&Xl[(r0 + 16) * LDS_STRIDE + kk];
#pragma unroll
    for (int m = 0; m < 8; ++m) {
      const int wi = (m * 16 + col) * H_DIM + kk;
      short8 ah = *(const short8*)&Wh[wi];
      short8 al = *(const short8*)&Wl[wi];
      acc[m][0] = __builtin_amdgcn_mfma_f32_16x16x32_bf16(ah, b0h, acc[m][0], 0, 0, 0);
      acc[m][0] = __builtin_amdgcn_mfma_f32_16x16x32_bf16(ah, b0l, acc[m][0], 0, 0, 0);
      acc[m][0] = __builtin_amdgcn_mfma_f32_16x16x32_bf16(al, b0h, acc[m][0], 0, 0, 0);
      acc[m][1] = __builtin_amdgcn_mfma_f32_16x16x32_bf16(ah, b1h, acc[m][1], 0, 0, 0);
      acc[m][1] = __builtin_amdgcn_mfma_f32_16x16x32_bf16(ah, b1l, acc[m][1], 0, 0, 0);
      acc[m][1] = __builtin_amdgcn_mfma_f32_16x16x32_bf16(al, b1h, acc[m][1], 0, 0, 0);
    }
  }

  // epilogue: s_e = sum_h W_rel[h]*elu(C[h,e]); C row = m*16+quad*4+reg
  float s0 = 0.f, s1 = 0.f;
#pragma unroll
  for (int m = 0; m < 8; ++m) {
    float4 wv = *(const float4*)(W_relation + m * 16 + quad * 4);
    s0 += wv.x * elu_f(acc[m][0][0]) + wv.y * elu_f(acc[m][0][1]) +
          wv.z * elu_f(acc[m][0][2]) + wv.w * elu_f(acc[m][0][3]);
    s1 += wv.x * elu_f(acc[m][1][0]) + wv.y * elu_f(acc[m][1][1]) +
          wv.z * elu_f(acc[m][1][2]) + wv.w * elu_f(acc[m][1][3]);
  }
  s0 += __shfl_xor(s0, 16); s0 += __shfl_xor(s0, 32);
  s1 += __shfl_xor(s1, 16); s1 += __shfl_xor(s1, 32);
  if (lane < 32) {
    long e = tile_base + wave * 32 + lane;
    float sv = (lane & 16) ? s1 : s0;
    int s = src_idx[e], d = dst_idx[e];
    atomicAdd(rel_logits + d, distribution[s] * sv);
  }
}

// ---------------------------------------------------------------------------
// Node pass (MFMA): K=896 in 7 phases of 128 (one per property p).
// state_logits[n] = sum_h W_state[h]*elu(C[h,n]) -- plain store, no atomics.
__global__ void __launch_bounds__(256) node_mfma_kernel(
    const float* __restrict__ node_attrs,  // [N][7][128]
    const ushort_t* __restrict__ Wh,       // [7][128][128] scaled
    const ushort_t* __restrict__ Wl,
    const float* __restrict__ W_state,     // [128]
    float* __restrict__ state_logits,      // [N]
    int N) {
  __shared__ __align__(16) ushort_t Xh[128 * LDS_STRIDE];
  __shared__ __align__(16) ushort_t Xl[128 * LDS_STRIDE];
  const int t = threadIdx.x;
  const long tile_base = (long)blockIdx.x * 128;
  const int lane = t & 63;
  const int wave = t >> 6;
  const int col = lane & 15;
  const int quad = lane >> 4;

  f32x4 acc[8][2];
#pragma unroll
  for (int m = 0; m < 8; ++m) {
    acc[m][0] = (f32x4){0.f, 0.f, 0.f, 0.f};
    acc[m][1] = (f32x4){0.f, 0.f, 0.f, 0.f};
  }
  const int r0 = wave * 32 + col;

  for (int p = 0; p < 7; ++p) {
    if (p) __syncthreads();  // previous phase's reads done before overwrite
#pragma unroll 4
    for (int i = 0; i < 16; ++i) {
      int f = i * 256 + t;
      int row = f >> 5;
      int k4 = (f & 31) * 4;
      long n = tile_base + row;
      float4 v;
      if (n < N) v = *(const float4*)(node_attrs + ((n * 7 + p) << 7) + k4);
      else       v = make_float4(0.f, 0.f, 0.f, 0.f);
      ushort4 h4, l4;
      split_bf16(v.x, h4.x, l4.x);
      split_bf16(v.y, h4.y, l4.y);
      split_bf16(v.z, h4.z, l4.z);
      split_bf16(v.w, h4.w, l4.w);
      int idx = row * LDS_STRIDE + k4;
      *(ushort4*)&Xh[idx] = h4;
      *(ushort4*)&Xl[idx] = l4;
    }
    __syncthreads();

    const ushort_t* Whp = Wh + p * (H_DIM * H_DIM);
    const ushort_t* Wlp = Wl + p * (H_DIM * H_DIM);
#pragma unroll
    for (int ks = 0; ks < 4; ++ks) {
      const int kk = ks * 32 + quad * 8;
      short8 b0h = *(const short8*)&Xh[r0 * LDS_STRIDE + kk];
      short8 b0l = *(const short8*)&Xl[r0 * LDS_STRIDE + kk];
      short8 b1h = *(const short8*)&Xh[(r0 + 16) * LDS_STRIDE + kk];
      short8 b1l = *(const short8*)&Xl[(r0 + 16) * LDS_STRIDE + kk];
#pragma unroll
      for (int m = 0; m < 8; ++m) {
        const int wi = (m * 16 + col) * H_DIM + kk;
        short8 ah = *(const short8*)&Whp[wi];
        short8 al = *(const short8*)&Wlp[wi];
        acc[m][0] = __builtin_amdgcn_mfma_f32_16x16x32_bf16(ah, b0h, acc[m][0], 0, 0, 0);
        acc[m][0] = __builtin_amdgcn_mfma_f32_16x16x32_bf16(ah, b0l, acc[m][0], 0, 0, 0);
        acc[m][0] = __builtin_amdgcn_mfma_f32_16x16x32_bf16(al, b0h, acc[m][0], 0, 0, 0);
        acc[m][1] = __builtin_amdgcn_mfma_f32_16x16x32_bf16(ah, b1h, acc[m][1], 0, 0, 0);
        acc[m][1] = __builtin_amdgcn_mfma_f32_16x16x32_bf16(ah, b1l, acc[m][1], 0, 0, 0);
        acc[m][1] = __builtin_amdgcn_mfma_f32_16x16x32_bf16(al, b1h, acc[m][1], 0, 0, 0);
      }
    }
  }

  float s0 = 0.f, s1 = 0.f;
#pragma unroll
  for (int m = 0; m < 8; ++m) {
    float4 wv = *(const float4*)(W_state + m * 16 + quad * 4);
    s0 += wv.x * elu_f(acc[m][0][0]) + wv.y * elu_f(acc[m][0][1]) +
          wv.z * elu_f(acc[m][0][2]) + wv.w * elu_f(acc[m][0][3]);
    s1 += wv.x * elu_f(acc[m][1][0]) + wv.y * elu_f(acc[m][1][1]) +
          wv.z * elu_f(acc[m][1][2]) + wv.w * elu_f(acc[m][1][3]);
  }
  s0 += __shfl_xor(s0, 16); s0 += __shfl_xor(s0, 32);
  s1 += __shfl_xor(s1, 16); s1 += __shfl_xor(s1, 32);
  if (lane < 32) {
    long n = tile_base + wave * 32 + lane;
    if (n < N) state_logits[n] = (lane & 16) ? s1 : s0;
  }
}

// ---------------------------------------------------------------------------
// Per-graph softmaxes + combine (unchanged from round 1 — it passed).
__device__ __forceinline__ float wave_red_max(float v) {
#pragma unroll
  for (int off = 32; off > 0; off >>= 1) v = fmaxf(v, __shfl_down(v, off));
  return v;
}
__device__ __forceinline__ float wave_red_sum(float v) {
#pragma unroll
  for (int off = 32; off > 0; off >>= 1) v += __shfl_down(v, off);
  return v;
}

__global__ void finalize_kernel(const float* __restrict__ state_logits,
                                const float* __restrict__ rel_logits,
                                const int* __restrict__ node_graph,
                                const float* __restrict__ prop_sim,
                                float* __restrict__ out, int N) {
  int g = blockIdx.x;
  __shared__ int bounds[2];
  if (threadIdx.x == 0) {
    int a = 0, b = N;
    while (a < b) { int m = (a + b) >> 1; if (node_graph[m] < g) a = m + 1; else b = m; }
    bounds[0] = a;
    b = N;
    while (a < b) { int m = (a + b) >> 1; if (node_graph[m] < g + 1) a = m + 1; else b = m; }
    bounds[1] = a;
  }
  __syncthreads();
  int lo = bounds[0], hi = bounds[1];
  if (lo >= hi) return;

  int lane = threadIdx.x & 63, w = threadIdx.x >> 6;
  __shared__ float redS[4], redR[4];

  float mS = -3.0e38f, mR = -3.0e38f;
  for (int i = lo + threadIdx.x; i < hi; i += blockDim.x) {
    mS = fmaxf(mS, state_logits[i]);
    mR = fmaxf(mR, rel_logits[i]);
  }
  mS = wave_red_max(mS); mR = wave_red_max(mR);
  if (lane == 0) { redS[w] = mS; redR[w] = mR; }
  __syncthreads();
  mS = fmaxf(fmaxf(redS[0], redS[1]), fmaxf(redS[2], redS[3]));
  mR = fmaxf(fmaxf(redR[0], redR[1]), fmaxf(redR[2], redR[3]));
  __syncthreads();

  float sS = 0.f, sR = 0.f;
  for (int i = lo + threadIdx.x; i < hi; i += blockDim.x) {
    sS += expf(state_logits[i] - mS);
    sR += expf(rel_logits[i] - mR);
  }
  sS = wave_red_sum(sS); sR = wave_red_sum(sR);
  if (lane == 0) { redS[w] = sS; redR[w] = sR; }
  __syncthreads();
  sS = redS[0] + redS[1] + redS[2] + redS[3];
  sR = redR[0] + redR[1] + redR[2] + redR[3];

  float p_rel = prop_sim[NPROP - 1];
  float invS = 1.0f / sS, invR = 1.0f / sR;
  for (int i = lo + threadIdx.x; i < hi; i += blockDim.x) {
    float ps = expf(state_logits[i] - mS) * invS;
    float pr = expf(rel_logits[i] - mR) * invR;
    out[i] = p_rel * pr + (1.0f - p_rel) * ps;
  }
}

// ---------------------------------------------------------------------------
extern "C" void kernel_launch(void* const* d_in, const int* in_sizes, int n_in,
                              void* d_out, int out_size, void* d_ws, size_t ws_size,
                              hipStream_t stream) {
  const float* node_attrs   = (const float*)d_in[0];  // [N][7][128]
  const float* edge_attrs   = (const float*)d_in[1];  // [E][128]
  const float* instruction  = (const float*)d_in[2];  // [128]
  const float* prop_embeds  = (const float*)d_in[3];  // [8][128]
  const float* distribution = (const float*)d_in[4];  // [N]
  const float* Ws_property  = (const float*)d_in[5];  // [8][128][128]
  const float* W_state      = (const float*)d_in[6];  // [128]
  const float* W_relation   = (const float*)d_in[7];  // [128]
  const int*   edge_indices = (const int*)d_in[8];    // [2][E]
  const int*   node_graph   = (const int*)d_in[9];    // [N] sorted

  int N = in_sizes[4];
  int E = in_sizes[1] / H_DIM;
  float* out = (float*)d_out;

  // workspace layout (16B-aligned chunks)
  char* w = (char*)d_ws;
  size_t nBytes = ((size_t)N * 4 + 15) & ~(size_t)15;
  float*    prop_sim     = (float*)w;                     // 256 B
  float*    state_logits = (float*)(w + 256);
  float*    rel_logits   = (float*)(w + 256 + nBytes);
  ushort_t* Wh           = (ushort_t*)(w + 256 + 2 * nBytes);
  ushort_t* Wl           = Wh + NPROP * H_DIM * H_DIM;

  hipMemsetAsync(rel_logits, 0, (size_t)N * 4, stream);

  prep_prop_sim<<<1, 512, 0, stream>>>(prop_embeds, instruction, prop_sim);
  prep_weights<<<NPROP * H_DIM * H_DIM / 256, 256, 0, stream>>>(
      Ws_property, instruction, prop_sim, Wh, Wl);

  node_mfma_kernel<<<(N + 127) / 128, 256, 0, stream>>>(
      node_attrs, Wh, Wl, W_state, state_logits, N);

  edge_mfma_kernel<<<E / 128, 256, 0, stream>>>(
      edge_attrs, Wh + 7 * H_DIM * H_DIM, Wl + 7 * H_DIM * H_DIM,
      W_relation, distribution, edge_indices, edge_indices + E, rel_logits);

  finalize_kernel<<<NGRAPHS, 256, 0, stream>>>(state_logits, rel_logits,
                                               node_graph, prop_sim, out, N);
}